// Round 13
// baseline (154.349 us; speedup 1.0000x reference)
//
#include <hip/hip_runtime.h>
#include <hip/hip_bf16.h>
#include <hip/hip_fp8.h>
#include <stdint.h>

// Shapes: b=2, n=5, k=5, q=75, t=196, c=384, s=k*t=980 (padded to 1024/class)
// M per b = 75*196 = 14700 (58 tiles of 256 rows). Outputs: logits[750] ++ cls_logits[750].
// Sim branch: fp8-e4m3 MX-scaled MFMA (scales=1.0); cls branch exact fp32.
//
// Round-23: PREP VECTORIZATION. R22's fusion cleared the tripwires (WRITE 5.7MB->379KB,
// P + third kernel eliminated) but total stayed ~154: non-gemm = 88us IDENTICAL across
// 3-kernel and 2-kernel builds -> final/gaps were ~0 and PREP owns ~85us of budget
// (traffic is only ~76MB = ~13us ideal; it runs at <1 TB/s effective).
// Cause (G13 applied to STORES): 16 lanes/row with scalar 4B stores. Verified
// algebraically: any aligned 4-consecutive-source-word run maps to ONE contiguous 16B
// dest granule in BOTH fqn (row-major) and fsnp (fragment order):
//   w=4g+m -> l16=(4g&15)+m, j=g>>2  =>  dest = (g>>3)*1024 + (g&1)*256
//           + (((g>>2)&1)*2 + ((g>>1)&1))*64 + m   (+ row base)    [shot]
//   dest = 4g+m                                                     [query]
// New prep: 8 lanes/row, runs g = l8+8t (t=0..2) -> 3x uint4 16B stores/lane,
// store instr = contiguous 128B per row; 12x float4 loads/lane (64B-line friendly);
// 3-shfl reduction. Blocks 2478 -> 1239. gemm byte-identical to R22 (65us, MfmaUtil
// ~34%, FETCH 13.9MB, WRITE 379KB).

typedef __attribute__((ext_vector_type(8))) int int8v;      // f8f6f4 A/B operand (32 fp8)
typedef __attribute__((ext_vector_type(4))) float f32x4;    // MFMA C/D frag

__device__ __forceinline__ unsigned pack4_fp8(float a, float b, float c, float d) {
    int r = __builtin_amdgcn_cvt_pk_fp8_f32(a, b, 0, false);   // bytes 0,1
    r = __builtin_amdgcn_cvt_pk_fp8_f32(c, d, r, true);        // bytes 2,3
    return (unsigned)r;
}

// ---------------- fused prep: norm (8 lanes/row, 16B stores) | proto | zero logits ----------------
__global__ void prep_kernel(const float* __restrict__ feat_query,
                            const float* __restrict__ feat_shot,
                            const float* __restrict__ x_shot,
                            unsigned* __restrict__ fqn,
                            unsigned* __restrict__ fsnp,
                            float* __restrict__ proto,
                            float* __restrict__ out) {
    const int blk  = blockIdx.x;
    const int tid  = threadIdx.x;
    const int lane = tid & 63;
    const int wv   = tid >> 6;

    if (blk < 1239) {                       // ---- token L2 norm -> fp8, 8 rows/wave ----
        const int tr = blk * 32 + wv * 8 + (lane >> 3);    // 0..39647
        const int l8 = lane & 7;
        if (tr >= 39640) return;

        const float* row;
        unsigned* o32;
        bool zero = false;
        bool shot = false;
        if (tr < 29400) {
            row = feat_query + (size_t)tr * 384;
            o32 = fqn + (size_t)tr * 96;
        } else {
            const int sp = tr - 29400;          // padded shot row: [bn][1024]
            const int bn = sp >> 10;
            const int s  = sp & 1023;           // col within class block
            row  = feat_shot + ((size_t)bn * 980 + s) * 384;
            zero = (s >= 980);
            shot = true;
            const int shh   = s >> 9;
            const int c     = s & 511;
            const int chunk = c >> 5;
            const int cl    = c & 31;
            o32 = fsnp + (size_t)bn * 98304 + shh * 49152 + chunk * 3072
                       + (cl >> 4) * 512 + (cl & 15) * 4;
        }

        // dest word offsets for the 3 runs g = l8 + 8t (16B granule each)
        int off[3];
#pragma unroll
        for (int t = 0; t < 3; ++t) {
            const int g = l8 + 8 * t;
            off[t] = shot ? ((g >> 3) * 1024 + (g & 1) * 256
                             + (((g >> 2) & 1) * 2 + ((g >> 1) & 1)) * 64)
                          : (4 * g);
        }

        if (zero) {
            const uint4 z = {0u, 0u, 0u, 0u};
#pragma unroll
            for (int t = 0; t < 3; ++t) *(uint4*)(o32 + off[t]) = z;
            return;
        }

        const float4* rf4 = (const float4*)row;
        float4 v[3][4];
        float ss = 0.f;
#pragma unroll
        for (int t = 0; t < 3; ++t) {
            const int g = l8 + 8 * t;
#pragma unroll
            for (int m = 0; m < 4; ++m) {
                v[t][m] = rf4[4 * g + m];
                ss += v[t][m].x * v[t][m].x + v[t][m].y * v[t][m].y
                    + v[t][m].z * v[t][m].z + v[t][m].w * v[t][m].w;
            }
        }
#pragma unroll
        for (int o = 1; o < 8; o <<= 1) ss += __shfl_xor(ss, o, 64);
        const float sc = 1.0f / fmaxf(sqrtf(ss), 1e-8f);
#pragma unroll
        for (int t = 0; t < 3; ++t) {
            uint4 wq;
            wq.x = pack4_fp8(v[t][0].x * sc, v[t][0].y * sc, v[t][0].z * sc, v[t][0].w * sc);
            wq.y = pack4_fp8(v[t][1].x * sc, v[t][1].y * sc, v[t][1].z * sc, v[t][1].w * sc);
            wq.z = pack4_fp8(v[t][2].x * sc, v[t][2].y * sc, v[t][2].z * sc, v[t][2].w * sc);
            wq.w = pack4_fp8(v[t][3].x * sc, v[t][3].y * sc, v[t][3].z * sc, v[t][3].w * sc);
            *(uint4*)(o32 + off[t]) = wq;
        }
    } else if (blk < 1242) {                // ---- proto = l2norm(mean_k x_shot), fp32 ----
        const int gw = (blk - 1239) * 4 + wv;
        if (gw >= 10) return;
        const float* base = x_shot + (size_t)gw * 5 * 384;
        float v[6];
        float ss = 0.f;
#pragma unroll
        for (int j = 0; j < 6; ++j) {
            float s = 0.f;
#pragma unroll
            for (int kk = 0; kk < 5; ++kk) s += base[kk * 384 + lane + 64 * j];
            s *= 0.2f;
            v[j] = s;
            ss += s * s;
        }
#pragma unroll
        for (int off = 1; off < 64; off <<= 1) ss += __shfl_xor(ss, off, 64);
        const float scale = 1.0f / fmaxf(sqrtf(ss), 1e-12f);
#pragma unroll
        for (int j = 0; j < 6; ++j) proto[(size_t)gw * 384 + lane + 64 * j] = v[j] * scale;
    } else {                                // ---- zero the logits accumulators ----
        for (int i = tid; i < 750; i += 256) out[i] = 0.f;
    }
}

// ---------------- fp8 GEMM + row-max + logits-mean | cls (fused; byte-identical to R22) ----------------
__global__ __launch_bounds__(256, 2) void gemm_kernel(const uint8_t* __restrict__ fqn,
                                                      const uint8_t* __restrict__ fsnp,
                                                      const float* __restrict__ xq,
                                                      const float* __restrict__ proto,
                                                      float* __restrict__ out) {
    const int p = blockIdx.x;

    if (p >= 580) {                         // ---- cls_logits blocks ----
        const int tid  = threadIdx.x;
        const int lane = tid & 63;
        const int wv   = tid >> 6;
        const int gw   = (p - 580) * 4 + wv;   // b*75+q
        if (gw >= 150) return;
        const float* row = xq + (size_t)gw * 384;
        float u[6];
        float ss = 0.f;
#pragma unroll
        for (int j = 0; j < 6; ++j) { u[j] = row[lane + 64 * j]; ss += u[j] * u[j]; }
#pragma unroll
        for (int off = 1; off < 64; off <<= 1) ss += __shfl_xor(ss, off, 64);
        const float scale = 1.0f / fmaxf(sqrtf(ss), 1e-12f);
#pragma unroll
        for (int j = 0; j < 6; ++j) u[j] *= scale;
        const int b = gw / 75;
        for (int n = 0; n < 5; ++n) {
            const float* pr = proto + (size_t)(b * 5 + n) * 384;
            float d = 0.f;
#pragma unroll
            for (int j = 0; j < 6; ++j) d += u[j] * pr[lane + 64 * j];
#pragma unroll
            for (int off = 1; off < 64; off <<= 1) d += __shfl_xor(d, off, 64);
            if (lane == 0) out[750 + gw * 5 + n] = 10.0f * d;
        }
        return;
    }

    // ---- XCD-chunked bijective decode: 580 = 4 chunks x 73 + 4 chunks x 72 ----
    const int c   = p & 7;
    const int pos = p >> 3;
    const int w   = (c < 4 ? c * 73 : 292 + (c - 4) * 72) + pos;
    const int b   = w / 290;                // 58 mt x 5 cls per b
    const int rem = w - b * 290;
    const int mt  = rem / 5;
    const int cls = rem - mt * 5;
    const int bc  = b * 5 + cls;
    const int m0  = mt * 256;

    const int tid  = threadIdx.x;
    const int lane = tid & 63;
    const int wv   = tid >> 6;
    const int l15  = lane & 15;
    const int hi   = lane >> 4;

    const uint8_t* Ag = fqn  + (size_t)b * 14700 * 384;
    const uint8_t* Bg = fsnp + (size_t)bc * 393216;
    const uint8_t* bp = Bg + lane * 16;    // + kg*4096 + j*1024 (kg = chunk*3+ks, 0..92)

    // ---- A fragments -> registers (one-time; wave wv holds rows m0+wv*64 .. +63) ----
    int8v A[4][3];
#pragma unroll
    for (int mi = 0; mi < 4; ++mi) {
        int row = m0 + wv * 64 + mi * 16 + l15;
        row = row < 14700 ? row : 14699;           // clamp; dead rows masked at epilogue
        const uint8_t* pa = Ag + (size_t)row * 384 + hi * 32;
#pragma unroll
        for (int ks = 0; ks < 3; ++ks) {
            const uint4 x = *(const uint4*)(pa + ks * 128);
            const uint4 y = *(const uint4*)(pa + ks * 128 + 16);
            A[mi][ks] = (int8v){(int)x.x, (int)x.y, (int)x.z, (int)x.w,
                                (int)y.x, (int)y.y, (int)y.z, (int)y.w};
        }
    }

    float rmax[4][4];
#pragma unroll
    for (int mi = 0; mi < 4; ++mi)
#pragma unroll
        for (int i = 0; i < 4; ++i) rmax[mi][i] = -3.0e38f;

    // ---- prologue: fill the 3-slot pipeline with k-steps 0,1,2 ----
    uint4 S[3][4];                          // statically indexed only
#pragma unroll
    for (int ks = 0; ks < 3; ++ks) {
        const uint8_t* p2 = bp + (size_t)ks * 4096;
#pragma unroll
        for (int j = 0; j < 4; ++j)
            S[ks][j] = *(const uint4*)(p2 + j * 1024);
    }

    for (int chunk = 0; chunk < 31; ++chunk) {
        f32x4 acc[4][2];
#pragma unroll
        for (int mi = 0; mi < 4; ++mi)
#pragma unroll
            for (int nf = 0; nf < 2; ++nf) acc[mi][nf] = (f32x4){0.f, 0.f, 0.f, 0.f};

#pragma unroll
        for (int ks = 0; ks < 3; ++ks) {
            const int8v Bf0 = (int8v){(int)S[ks][0].x, (int)S[ks][0].y,
                                      (int)S[ks][0].z, (int)S[ks][0].w,
                                      (int)S[ks][1].x, (int)S[ks][1].y,
                                      (int)S[ks][1].z, (int)S[ks][1].w};
            const int8v Bf1 = (int8v){(int)S[ks][2].x, (int)S[ks][2].y,
                                      (int)S[ks][2].z, (int)S[ks][2].w,
                                      (int)S[ks][3].x, (int)S[ks][3].y,
                                      (int)S[ks][3].z, (int)S[ks][3].w};
#pragma unroll
            for (int mi = 0; mi < 4; ++mi) {
                acc[mi][0] = __builtin_amdgcn_mfma_scale_f32_16x16x128_f8f6f4(
                    A[mi][ks], Bf0, acc[mi][0],
                    0, 0, 0, 0x7F7F7F7F, 0, 0x7F7F7F7F);
                acc[mi][1] = __builtin_amdgcn_mfma_scale_f32_16x16x128_f8f6f4(
                    A[mi][ks], Bf1, acc[mi][1],
                    0, 0, 0, 0x7F7F7F7F, 0, 0x7F7F7F7F);
            }
            // re-issue slot ks for k-step chunk*3+ks+3 (clamped tail)
            {
                const int kn = chunk * 3 + ks + 3;
                const int kc = kn < 93 ? kn : 92;
                const uint8_t* p2 = bp + (size_t)kc * 4096;
#pragma unroll
                for (int j = 0; j < 4; ++j)
                    S[ks][j] = *(const uint4*)(p2 + j * 1024);
            }
        }

        // fold row-max (mask padded cols >= 980; only chunk 30 / nf=1 can fail)
#pragma unroll
        for (int nf = 0; nf < 2; ++nf) {
            if (chunk * 32 + nf * 16 + l15 < 980) {
#pragma unroll
                for (int mi = 0; mi < 4; ++mi)
#pragma unroll
                    for (int i = 0; i < 4; ++i)
                        rmax[mi][i] = fmaxf(rmax[mi][i], acc[mi][nf][i]);
            }
        }
    }

    // ---- epilogue: max over 16 col-lanes -> per-q bucket sums -> atomicAdd(out) ----
    const int start = m0 + wv * 64;             // wave's first row
    const int qbase = start / 196;
    float a0 = 0.f, a1 = 0.f;
#pragma unroll
    for (int mi = 0; mi < 4; ++mi)
#pragma unroll
        for (int i = 0; i < 4; ++i) {
            float v = rmax[mi][i];
#pragma unroll
            for (int off = 1; off < 16; off <<= 1) v = fmaxf(v, __shfl_xor(v, off, 64));
            if (l15 == 0) {
                const int row = start + mi * 16 + hi * 4 + i;
                if (row < 14700) {
                    if (row / 196 == qbase) a0 += v; else a1 += v;
                }
            }
        }
    if (l15 == 0 && start < 14700) {
        atomicAdd(&out[(b * 75 + qbase) * 5 + cls], a0 * (1.0f / 196.0f));
        const int rend = start + 63 < 14699 ? start + 63 : 14699;
        if (rend / 196 != qbase)
            atomicAdd(&out[(b * 75 + qbase + 1) * 5 + cls], a1 * (1.0f / 196.0f));
    }
}

extern "C" void kernel_launch(void* const* d_in, const int* in_sizes, int n_in,
                              void* d_out, int out_size, void* d_ws, size_t ws_size,
                              hipStream_t stream) {
    const float* feat_shot  = (const float*)d_in[0];  // [2,5,5,196,384]
    const float* feat_query = (const float*)d_in[1];  // [2,75,196,384]
    const float* x_shot     = (const float*)d_in[2];  // [2,5,5,384]
    const float* x_query    = (const float*)d_in[3];  // [2,75,384]
    float* out = (float*)d_out;
    char* ws = (char*)d_ws;

    // ws layout (15.2 MiB used; P eliminated)
    uint8_t*  fqn   = (uint8_t*)ws;                     // 29400*384  = 11,289,600 B (fp8, row-major)
    uint8_t*  fsnp  = (uint8_t*)(ws + 11289600);        // 10240*384  =  3,932,160 B (fp8, FRAGMENT order)
    float*    proto = (float*)(ws + 15221760);          //      3,840 f32

    prep_kernel<<<1243, 256, 0, stream>>>(feat_query, feat_shot, x_shot,
                                          (unsigned*)fqn, (unsigned*)fsnp, proto, out);
    gemm_kernel<<<618, 256, 0, stream>>>(fqn, fsnp, x_query, proto, out);
}